// Round 1
// baseline (833.023 us; speedup 1.0000x reference)
//
#include <hip/hip_runtime.h>
#include <stdint.h>

#define DEV __device__ __forceinline__

typedef _Float16 half2_t __attribute__((ext_vector_type(2)));
typedef _Float16 half4_t __attribute__((ext_vector_type(4)));
typedef __bf16   bf16x8  __attribute__((ext_vector_type(8)));
typedef float    floatx4 __attribute__((ext_vector_type(4)));
typedef float    floatx2 __attribute__((ext_vector_type(2)));

DEV float fdot2f(half2_t a, half2_t b, float c) {
#if __has_builtin(__builtin_amdgcn_fdot2)
  return __builtin_amdgcn_fdot2(a, b, c, false);
#else
  return c + (float)a[0] * (float)b[0] + (float)a[1] * (float)b[1];
#endif
}

DEV uint32_t f2bf(float f) {  // fp32 -> bf16 bits, RNE
  uint32_t u = __float_as_uint(f);
  return (u + 0x7FFFu + ((u >> 16) & 1u)) >> 16;
}

// ---------------------------------------------------------------------------
// Correlation, big levels (l0,l1,l2): tile 16x16 px, thread owns 2 px,
// channel-split across blocks, partials to ws. f16 channel-pairs in LDS + dot2.
// ---------------------------------------------------------------------------
struct CorrCfg {
  int wg_start[3];
  int S[3], C[3], tiles_x[3], tiles_pb[3], cpl[3];
  long long poff[3];
};

template<int TH, int TWD>
__global__ __launch_bounds__(TH*TWD/2)
void corr_big_kernel(CorrCfg cfg,
                     const float* __restrict__ x0, const float* __restrict__ xp0,
                     const float* __restrict__ x1, const float* __restrict__ xp1,
                     const float* __restrict__ x2, const float* __restrict__ xp2,
                     float* __restrict__ partial)
{
  constexpr int NT = TH*TWD/2;
  constexpr int HW = TWD + 6;    // used halo cols
  constexpr int ST = TWD + 10;   // padded LDS row stride (bank spread)
  __shared__ half2_t lds[2][TH+6][ST] __attribute__((aligned(16)));

  int wg = blockIdx.x;
  int lvl = (wg >= cfg.wg_start[2]) ? 2 : (wg >= cfg.wg_start[1]) ? 1 : 0;
  wg -= cfg.wg_start[lvl];
  const float* X  = lvl==0 ? x0  : lvl==1 ? x1  : x2;
  const float* XP = lvl==0 ? xp0 : lvl==1 ? xp1 : xp2;
  const int S = cfg.S[lvl], C = cfg.C[lvl];
  const int txc = cfg.tiles_x[lvl], tpb = cfg.tiles_pb[lvl], cpl = cfg.cpl[lvl];
  const int per_split = 8 * tpb;
  const int sp = wg / per_split;
  const int rem = wg - sp*per_split;
  const int b = rem / tpb;
  const int t = rem - b*tpb;
  const int y0 = (t / txc) * TH, x0t = (t % txc) * TWD;
  const int tid = threadIdx.x;
  const int tx = tid % (TWD/2), ty = tid / (TWD/2);
  const int cbase = sp * cpl;
  const size_t SS = (size_t)S*S;
  const float* Xb  = X  + (size_t)b*C*SS;
  const float* XPb = XP + (size_t)b*C*SS;
  const int py = y0 + ty, px = x0t + 2*tx;

  floatx2 acc[49];
  #pragma unroll
  for (int d = 0; d < 49; ++d) acc[d] = (floatx2)0.0f;

  for (int c0 = 0; c0 < cpl; c0 += 4) {
    __syncthreads();
    #pragma unroll
    for (int pr = 0; pr < 2; ++pr) {   // two channel-pairs per chunk
      const float* p0 = XPb + (size_t)(cbase + c0 + 2*pr)*SS;
      const float* p1 = p0 + SS;
      for (int i = tid; i < (TH+6)*HW; i += NT) {
        int r = i / HW, cc = i - r*HW;
        int gy = y0 + r - 3, gx = x0t + cc - 3;
        float v0 = 0.f, v1 = 0.f;
        if (gy >= 0 && gy < S && gx >= 0 && gx < S) {
          size_t o = (size_t)gy*S + gx;
          v0 = p0[o]; v1 = p1[o];
        }
        half2_t pk = {(_Float16)v0, (_Float16)v1};
        lds[pr][r][cc] = pk;
      }
    }
    __syncthreads();
    #pragma unroll
    for (int pr = 0; pr < 2; ++pr) {
      const float* q0 = Xb + (size_t)(cbase + c0 + 2*pr)*SS + (size_t)py*S + px;
      const float* q1 = q0 + SS;
      half2_t xq0 = {(_Float16)q0[0], (_Float16)q1[0]};   // (ch, ch+1) at px
      half2_t xq1 = {(_Float16)q0[1], (_Float16)q1[1]};   // at px+1
      #pragma unroll
      for (int di = 0; di < 7; ++di) {
        const half2_t* row = &lds[pr][ty+di][2*tx];
        half2_t w[8];
        #pragma unroll
        for (int k = 0; k < 4; ++k) {    // 4x 8B LDS loads (aligned)
          half4_t v = *(const half4_t*)(row + 2*k);
          w[2*k]   = __builtin_shufflevector(v, v, 0, 1);
          w[2*k+1] = __builtin_shufflevector(v, v, 2, 3);
        }
        #pragma unroll
        for (int dj = 0; dj < 7; ++dj) {
          acc[di*7+dj].x = fdot2f(xq0, w[dj],   acc[di*7+dj].x);
          acc[di*7+dj].y = fdot2f(xq1, w[dj+1], acc[di*7+dj].y);
        }
      }
    }
  }
  float* P = partial + cfg.poff[lvl] + ((size_t)sp*8 + b)*49*SS + (size_t)py*S + px;
  #pragma unroll
  for (int d = 0; d < 49; ++d)
    *(floatx2*)(P + (size_t)d*SS) = acc[d];
}

// ---------------------------------------------------------------------------
// Correlation, small levels (l3,l4,l5): one thread per (b,d,y,x), loop C.
// ---------------------------------------------------------------------------
struct CSCfg {
  int blk_start[3];
  int S[3], C[3];
  long long poff[3];
};
__global__ __launch_bounds__(256)
void corr_small_kernel(CSCfg cfg,
    const float* __restrict__ x3, const float* __restrict__ xp3,
    const float* __restrict__ x4, const float* __restrict__ xp4,
    const float* __restrict__ x5, const float* __restrict__ xp5,
    float* __restrict__ partial)
{
  int blk = blockIdx.x;
  int lvl = (blk >= cfg.blk_start[2]) ? 2 : (blk >= cfg.blk_start[1]) ? 1 : 0;
  int i = (blk - cfg.blk_start[lvl])*256 + threadIdx.x;
  const int S = cfg.S[lvl], C = cfg.C[lvl];
  const int SS = S*S;
  if (i >= 8*49*SS) return;
  const float* X  = lvl==0 ? x3  : lvl==1 ? x4  : x5;
  const float* XP = lvl==0 ? xp3 : lvl==1 ? xp4 : xp5;
  int xc = i % S, yc = (i/S) % S, d = (i/SS) % 49, b = i/(49*SS);
  int yy = yc + d/7 - 3, xx = xc + (d%7) - 3;
  float s = 0.f;
  if (yy >= 0 && yy < S && xx >= 0 && xx < S) {
    const float* xb = X  + (size_t)b*C*SS + (size_t)yc*S + xc;
    const float* pb = XP + (size_t)b*C*SS + (size_t)yy*S + xx;
    #pragma unroll 4
    for (int c = 0; c < C; ++c) s += xb[(size_t)c*SS] * pb[(size_t)c*SS];
  }
  partial[cfg.poff[lvl] + i] = s;
}

// ---------------------------------------------------------------------------
// Weight pack: w[196][98][3][3] fp32 -> bf16 MFMA B-fragments
// layout [lvl][t:14][s:36][lane:64][j:8], k = tap*128 + ch, N padded to 224.
// ---------------------------------------------------------------------------
__global__ __launch_bounds__(256)
void pack_w_kernel(const float* __restrict__ w0, const float* __restrict__ w1,
                   const float* __restrict__ w2, const float* __restrict__ w3,
                   const float* __restrict__ w4, const float* __restrict__ w5,
                   uint16_t* __restrict__ wpack)
{
  int idx = blockIdx.x*256 + threadIdx.x;
  int lvl = idx / 258048;
  int e = idx - lvl*258048;
  const float* W = lvl==0?w0:lvl==1?w1:lvl==2?w2:lvl==3?w3:lvl==4?w4:w5;
  int j = e & 7, lane = (e >> 3) & 63, rest = e >> 9;
  int s = rest % 36, tt = rest / 36;
  int n  = tt*16 + (lane & 15);
  int ch = (s & 3)*32 + (lane >> 4)*8 + j;
  int tap = s >> 2, ky = tap/3, kx = tap - 3*ky;
  float v = 0.f;
  if (n < 196 && ch < 98) v = W[((n*98 + ch)*3 + ky)*3 + kx];
  wpack[idx] = (uint16_t)f2bf(v);
}

// ---------------------------------------------------------------------------
// Pass2: sum partials -> leaky_relu -> corr to d_out (fp32) + build padded
// channels-last bf16 lstm_in [b][y+2][x+2][128] (corr|h|zeros, halo zeros).
// ---------------------------------------------------------------------------
struct P2Cfg {
  int blk_start[7];
  int S[6], nsplit[6];
  long long poff[6], lstm_off[6], corr_off[6];
  const float* h[6];
};
__global__ __launch_bounds__(64)
void pass2_kernel(P2Cfg cfg, const float* __restrict__ partial,
                  uint32_t* __restrict__ lstm, float* __restrict__ dout)
{
  int blk = blockIdx.x;
  int lvl = 0;
  while (lvl < 5 && blk >= cfg.blk_start[lvl+1]) ++lvl;
  int i = (blk - cfg.blk_start[lvl])*64 + threadIdx.x;
  const int S = cfg.S[lvl], Sp = S + 2;
  if (i >= 8*Sp*Sp) return;
  int b = i / (Sp*Sp), rr = i - b*Sp*Sp;
  int yy = rr / Sp, xx = rr - yy*Sp;
  uint32_t* Ld = lstm + (cfg.lstm_off[lvl] >> 1) + (size_t)i*64;
  if (yy == 0 || yy > S || xx == 0 || xx > S) {
    #pragma unroll
    for (int k = 0; k < 64; ++k) Ld[k] = 0u;
    return;
  }
  int y = yy - 1, x = xx - 1;
  const size_t SS = (size_t)S*S;
  const int nsp = cfg.nsplit[lvl];
  const float* P = partial + cfg.poff[lvl] + (size_t)b*49*SS + (size_t)y*S + x;
  const size_t spstride = (size_t)8*49*SS;
  float* co = dout + cfg.corr_off[lvl] + (size_t)b*49*SS + (size_t)y*S + x;
  float cv[49];
  #pragma unroll
  for (int ch = 0; ch < 49; ++ch) {
    float s = 0.f;
    for (int sp = 0; sp < nsp; ++sp) s += P[(size_t)ch*SS + (size_t)sp*spstride];
    s = s < 0.f ? 0.01f*s : s;
    cv[ch] = s;
    co[(size_t)ch*SS] = s;
  }
  const float* H = cfg.h[lvl] + (size_t)b*49*SS + (size_t)y*S + x;
  #pragma unroll
  for (int k = 0; k < 64; ++k) {
    const int c0 = 2*k, c1 = 2*k + 1;
    float v0 = c0 < 49 ? cv[c0] : (c0 < 98 ? H[(size_t)(c0-49)*SS] : 0.f);
    float v1 = c1 < 49 ? cv[c1] : (c1 < 98 ? H[(size_t)(c1-49)*SS] : 0.f);
    Ld[k] = f2bf(v0) | (f2bf(v1) << 16);
  }
}

// ---------------------------------------------------------------------------
// Conv 3x3 (98->196) as implicit GEMM, bf16 MFMA 16x16x32, K = 9*128 = 1152,
// N padded to 224. No LDS, no barriers: A-frags direct from channels-last
// lstm_in, B-frags from pre-packed weights (L2-resident).
// Wave tile: mfc M-frags x 7 N-tiles. acc: 112 VGPR.
// ---------------------------------------------------------------------------
struct CCfg {
  int wg_start[7];
  int S[6], tiles_x[6], tiles_pb[6], lwsh[6], mfc[6], mgrp[6];
  long long lstm_off[6], wp_off[6], conv_off[6];
};
__global__ __launch_bounds__(256)
void conv_kernel(CCfg cfg, const uint16_t* __restrict__ lstm,
                 const uint16_t* __restrict__ wpack, float* __restrict__ cout)
{
  int wg = blockIdx.x;
  int lvl = 0;
  while (lvl < 5 && wg >= cfg.wg_start[lvl+1]) ++lvl;
  wg -= cfg.wg_start[lvl];
  const int S = cfg.S[lvl], Sp = S + 2;
  const int lwsh = cfg.lwsh[lvl], msk = (1 << lwsh) - 1;
  const int tpb = cfg.tiles_pb[lvl];
  const int b = wg / tpb, t = wg - b*tpb;
  const int ty0 = (t / cfg.tiles_x[lvl]) * 8;
  const int tx0 = (t % cfg.tiles_x[lvl]) << lwsh;
  const int wave = threadIdx.x >> 6, lane = threadIdx.x & 63;
  const int nhalf = wave & 1, mhalf = wave >> 1;
  const int mfc = cfg.mfc[lvl];
  if (mhalf >= cfg.mgrp[lvl]) return;
  const int mi = lane & 15, q = lane >> 4;
  const int SS = S*S;
  const uint16_t* lb = lstm + cfg.lstm_off[lvl] + (size_t)b*Sp*Sp*128;
  int aoff[4];
  #pragma unroll
  for (int mf = 0; mf < 4; ++mf) {
    int p = mhalf*64 + mf*16 + mi;
    int pc = p < SS ? p : 0;                 // clamp (l5 pad)
    int y = ty0 + (pc >> lwsh), xx = tx0 + (pc & msk);
    aoff[mf] = (y*Sp + xx)*128 + q*8;
  }
  const uint16_t* wb = wpack + cfg.wp_off[lvl]
                     + (size_t)(nhalf*7)*36*512 + (size_t)lane*8;
  floatx4 acc[4][7];
  #pragma unroll
  for (int mf = 0; mf < 4; ++mf)
    #pragma unroll
    for (int nt = 0; nt < 7; ++nt) acc[mf][nt] = (floatx4)0.0f;

  for (int tap = 0; tap < 9; ++tap) {
    const int ky = tap/3, kx = tap - 3*(tap/3);
    const int to = (ky*Sp + kx)*128;
    #pragma unroll
    for (int cs = 0; cs < 4; ++cs) {
      const int s = tap*4 + cs;
      const int ao = to + cs*32;
      bf16x8 av[4]; bf16x8 bv[7];
      #pragma unroll
      for (int mf = 0; mf < 4; ++mf)
        if (mf < mfc) av[mf] = *(const bf16x8*)(lb + aoff[mf] + ao);
      #pragma unroll
      for (int nt = 0; nt < 7; ++nt)
        bv[nt] = *(const bf16x8*)(wb + (size_t)(nt*36 + s)*512);
      #pragma unroll
      for (int nt = 0; nt < 7; ++nt)
        #pragma unroll
        for (int mf = 0; mf < 4; ++mf)
          if (mf < mfc)
            acc[mf][nt] = __builtin_amdgcn_mfma_f32_16x16x32_bf16(
                              av[mf], bv[nt], acc[mf][nt], 0, 0, 0);
    }
  }
  float* co = cout + cfg.conv_off[lvl] + (size_t)b*196*SS;
  #pragma unroll
  for (int mf = 0; mf < 4; ++mf) {
    if (mf < mfc) {
      #pragma unroll
      for (int nt = 0; nt < 7; ++nt) {
        const int n = nhalf*112 + nt*16 + mi;
        if (n < 196) {
          #pragma unroll
          for (int r = 0; r < 4; ++r) {
            const int p = mhalf*64 + mf*16 + q*4 + r;   // D: row=q*4+r, col=lane&15
            if (p < SS) {
              const int y = ty0 + (p >> lwsh), xx = tx0 + (p & msk);
              co[(size_t)n*SS + y*S + xx] = acc[mf][nt][r];
            }
          }
        }
      }
    }
  }
}

// ---------------------------------------------------------------------------
// LSTM gates: conv + bias -> i,f,o,g -> h_next, c_next into d_out.
// ---------------------------------------------------------------------------
struct GCfg {
  int blk_start[7];
  int S[6];
  long long conv_off[6], h_off[6], c_off[6];
  const float* cpre[6]; const float* bias[6];
};
__global__ __launch_bounds__(256)
void gate_kernel(GCfg cfg, const float* __restrict__ convout, float* __restrict__ dout)
{
  int blk = blockIdx.x;
  int lvl = 0;
  while (lvl < 5 && blk >= cfg.blk_start[lvl+1]) ++lvl;
  int e = (blk - cfg.blk_start[lvl])*256 + threadIdx.x;
  const int S = cfg.S[lvl];
  const int SS = S*S;
  if (e >= 8*49*SS) return;
  int b = e / (49*SS);
  int r1 = e - b*49*SS;
  int ch = r1 / SS;
  int p  = r1 - ch*SS;
  const float* cv = convout + cfg.conv_off[lvl] + ((size_t)b*196 + ch)*SS + p;
  const float* bb = cfg.bias[lvl];
  float ci  = cv[0]              + bb[ch];
  float cf  = cv[(size_t)49*SS]  + bb[ch+49];
  float co_ = cv[(size_t)98*SS]  + bb[ch+98];
  float cg  = cv[(size_t)147*SS] + bb[ch+147];
  float ig = 1.f/(1.f + __expf(-ci));
  float fg = 1.f/(1.f + __expf(-cf));
  float og = 1.f/(1.f + __expf(-co_));
  float g  = 1.f - 2.f/(__expf(2.f*cg) + 1.f);
  float cp = cfg.cpre[lvl][e];
  float cn = fg*cp + ig*g;
  float hn = og * (1.f - 2.f/(__expf(2.f*cn) + 1.f));
  dout[cfg.h_off[lvl] + e] = hn;
  dout[cfg.c_off[lvl] + e] = cn;
}

// ---------------------------------------------------------------------------
extern "C" void kernel_launch(void* const* d_in, const int* in_sizes, int n_in,
                              void* d_out, int out_size, void* d_ws, size_t ws_size,
                              hipStream_t stream)
{
  const float *x[6], *xp[6], *h[6], *cpre[6], *w[6], *bias[6];
  for (int l = 0; l < 6; ++l) {
    x[l]    = (const float*)d_in[6*l + 0];
    xp[l]   = (const float*)d_in[6*l + 1];
    h[l]    = (const float*)d_in[6*l + 2];
    cpre[l] = (const float*)d_in[6*l + 3];
    w[l]    = (const float*)d_in[6*l + 4];
    bias[l] = (const float*)d_in[6*l + 5];
  }
  static const int SL[6] = {64,32,16,8,4,2};
  static const int CL[6] = {512,1024,512,256,256,256};
  static const int NSPL[6] = {4,8,16,1,1,1};

  long long hsz[6], lstm_off[6], conv_off[6], h_off[6], poff[6];
  long long a1 = 0, a2 = 0, a3 = 0, pa = 0;
  for (int l = 0; l < 6; ++l) {
    int S = SL[l], Sp = S + 2;
    hsz[l] = 8LL*49*S*S;
    lstm_off[l] = a1; a1 += 8LL*Sp*Sp*128;
    conv_off[l] = a2; a2 += 8LL*196*S*S;
    h_off[l]    = a3; a3 += hsz[l];
  }
  for (int l = 0; l < 6; ++l) { poff[l] = pa; pa += (long long)NSPL[l]*hsz[l]; }
  const long long GRP = a3;            // 2,140,320 floats per output group
  const long long LSTM_ELEMS = a1;     // 6,131,712 bf16

  // ws layout: [lstm bf16][wpack bf16][partial fp32 / convout fp32 (aliased)]
  uint16_t* lstm  = (uint16_t*)d_ws;
  uint16_t* wpack = (uint16_t*)((char*)d_ws + LSTM_ELEMS*2);
  float* partial  = (float*)((char*)d_ws + LSTM_ELEMS*2 + 6LL*258048*2);
  float* convout  = partial;  // partial fully consumed by pass2 before conv writes
  float* dout = (float*)d_out;

  // corr big (l0,l1,l2)
  CorrCfg ccfg;
  {
    static const int tpb[3] = {16, 4, 1};
    static const int txx[3] = {4, 2, 1};
    int start = 0;
    for (int l = 0; l < 3; ++l) {
      ccfg.wg_start[l] = start;
      ccfg.S[l] = SL[l]; ccfg.C[l] = CL[l];
      ccfg.tiles_x[l] = txx[l]; ccfg.tiles_pb[l] = tpb[l];
      ccfg.cpl[l] = CL[l]/NSPL[l];
      ccfg.poff[l] = poff[l];
      start += NSPL[l]*8*tpb[l];
    }
    corr_big_kernel<16,16><<<start, 128, 0, stream>>>(
        ccfg, x[0],xp[0], x[1],xp[1], x[2],xp[2], partial);
  }
  // corr small (l3..l5)
  {
    CSCfg scfg; int start = 0;
    for (int l = 0; l < 3; ++l) {
      scfg.blk_start[l] = start;
      scfg.S[l] = SL[l+3]; scfg.C[l] = CL[l+3];
      scfg.poff[l] = poff[l+3];
      start += (int)((hsz[l+3] + 255)/256);
    }
    corr_small_kernel<<<start, 256, 0, stream>>>(
        scfg, x[3],xp[3], x[4],xp[4], x[5],xp[5], partial);
  }
  // weight pack
  pack_w_kernel<<<6048, 256, 0, stream>>>(w[0],w[1],w[2],w[3],w[4],w[5], wpack);
  // pass2: partial sums -> leaky -> corr out + lstm_in
  {
    P2Cfg p2; int start = 0;
    for (int l = 0; l < 6; ++l) {
      p2.blk_start[l] = start;
      int Sp = SL[l] + 2;
      start += (8*Sp*Sp + 63)/64;
      p2.S[l] = SL[l]; p2.nsplit[l] = NSPL[l];
      p2.poff[l] = poff[l]; p2.lstm_off[l] = lstm_off[l];
      p2.corr_off[l] = 2*GRP + h_off[l];
      p2.h[l] = h[l];
    }
    p2.blk_start[6] = start;
    pass2_kernel<<<start, 64, 0, stream>>>(p2, partial, (uint32_t*)lstm, dout);
  }
  // conv (all levels, one launch)
  {
    CCfg cc;
    static const int ctpb[6] = {32, 8, 2, 1, 1, 1};
    static const int ctx[6]  = {4, 2, 1, 1, 1, 1};
    static const int clw[6]  = {4, 4, 4, 3, 2, 1};
    static const int cmfc[6] = {4, 4, 4, 4, 1, 1};
    static const int cmg[6]  = {2, 2, 2, 1, 1, 1};
    int start = 0;
    for (int l = 0; l < 6; ++l) {
      cc.wg_start[l] = start; start += 8*ctpb[l];
      cc.S[l] = SL[l]; cc.tiles_x[l] = ctx[l]; cc.tiles_pb[l] = ctpb[l];
      cc.lwsh[l] = clw[l]; cc.mfc[l] = cmfc[l]; cc.mgrp[l] = cmg[l];
      cc.lstm_off[l] = lstm_off[l];
      cc.wp_off[l] = 258048LL*l;
      cc.conv_off[l] = conv_off[l];
    }
    cc.wg_start[6] = start;
    conv_kernel<<<start, 256, 0, stream>>>(cc, lstm, wpack, convout);
  }
  // gates
  {
    GCfg gc; int start = 0;
    for (int l = 0; l < 6; ++l) {
      gc.blk_start[l] = start;
      start += (int)((hsz[l] + 255)/256);
      gc.S[l] = SL[l];
      gc.conv_off[l] = conv_off[l];
      gc.h_off[l] = h_off[l];
      gc.c_off[l] = GRP + h_off[l];
      gc.cpre[l] = cpre[l];
      gc.bias[l] = bias[l];
    }
    gc.blk_start[6] = start;
    gate_kernel<<<start, 256, 0, stream>>>(gc, convout, dout);
  }
  (void)in_sizes; (void)n_in; (void)out_size; (void)ws_size;
}

// Round 2
// 530.170 us; speedup vs baseline: 1.5712x; 1.5712x over previous
//
#include <hip/hip_runtime.h>
#include <stdint.h>

#define DEV __device__ __forceinline__

typedef _Float16 half2_t __attribute__((ext_vector_type(2)));
typedef _Float16 half4_t __attribute__((ext_vector_type(4)));
typedef __bf16   bf16x8  __attribute__((ext_vector_type(8)));
typedef float    floatx4 __attribute__((ext_vector_type(4)));
typedef float    floatx2 __attribute__((ext_vector_type(2)));

DEV float fdot2f(half2_t a, half2_t b, float c) {
#if __has_builtin(__builtin_amdgcn_fdot2)
  return __builtin_amdgcn_fdot2(a, b, c, false);
#else
  return c + (float)a[0] * (float)b[0] + (float)a[1] * (float)b[1];
#endif
}

DEV uint32_t f2bf(float f) {  // fp32 -> bf16 bits, RNE
  uint32_t u = __float_as_uint(f);
  return (u + 0x7FFFu + ((u >> 16) & 1u)) >> 16;
}

DEV half2_t mkh2(float a, float b) {
  half2_t r; r[0] = (_Float16)a; r[1] = (_Float16)b; return r;
}

// ---------------------------------------------------------------------------
// Correlation (all levels, one launch).
// Big levels (l0,l1,l2): 16x16 px tile, 128 thr (2 px/thr), channel-split
// across blocks, double-buffered LDS + register-staged global prefetch
// (loads for chunk k+2 issue while computing chunk k; 1 barrier/chunk).
// Small levels (l3..l5): one thread per (b,d,y,x), loop C.
// ---------------------------------------------------------------------------
struct CorrCfg {
  const float* gx[6]; const float* gxp[6];
  int wg_start[3];    // big-level block starts
  int small_start[3]; // small-level block starts
  int S[3], C[3], tiles_x[3], tiles_pb[3], cpl[3];
  int sS[3], sC[3];
  long long poff[3], spoff[3];
};

template<int TH, int TWD>
__global__ __launch_bounds__(128)
void corr_kernel(CorrCfg cfg, float* __restrict__ partial)
{
  int wg = blockIdx.x;
  if (wg >= cfg.small_start[0]) {
    // ---- small path ----
    int lvl = (wg >= cfg.small_start[2]) ? 2 : (wg >= cfg.small_start[1]) ? 1 : 0;
    long long i = (long long)(wg - cfg.small_start[lvl])*128 + threadIdx.x;
    const int S = cfg.sS[lvl], C = cfg.sC[lvl], SS = S*S;
    if (i >= (long long)8*49*SS) return;
    const float* X  = cfg.gx[lvl+3];
    const float* XP = cfg.gxp[lvl+3];
    int xc_ = (int)(i % S); int yc = (int)((i/S) % S);
    int d = (int)((i/SS) % 49); int b = (int)(i/((long long)49*SS));
    int yy = yc + d/7 - 3, xx = xc_ + (d%7) - 3;
    float s = 0.f;
    if (yy >= 0 && yy < S && xx >= 0 && xx < S) {
      const float* xb = X  + (size_t)b*C*SS + (size_t)yc*S + xc_;
      const float* pb = XP + (size_t)b*C*SS + (size_t)yy*S + xx;
      #pragma unroll 4
      for (int c = 0; c < C; ++c) s += xb[(size_t)c*SS] * pb[(size_t)c*SS];
    }
    partial[cfg.spoff[lvl] + i] = s;
    return;
  }
  // ---- big path ----
  constexpr int NT  = 128;
  constexpr int HWC = TWD + 6;          // 22 halo cols used
  constexpr int ST  = TWD + 10;         // 26-dword LDS row stride
  constexpr int NPOS = (TH+6)*HWC;      // 484
  constexpr int PER  = (NPOS + NT - 1)/NT;  // 4
  __shared__ half2_t ldsbuf[2][2][(TH+6)*ST] __attribute__((aligned(16)));

  int lvl = (wg >= cfg.wg_start[2]) ? 2 : (wg >= cfg.wg_start[1]) ? 1 : 0;
  wg -= cfg.wg_start[lvl];
  const float* X  = cfg.gx[lvl];
  const float* XP = cfg.gxp[lvl];
  const int S = cfg.S[lvl], C = cfg.C[lvl];
  const int txc = cfg.tiles_x[lvl], tpb = cfg.tiles_pb[lvl], cpl = cfg.cpl[lvl];
  const int per_split = 8 * tpb;
  const int sp = wg / per_split;
  const int rem = wg - sp*per_split;
  const int b = rem / tpb;
  const int t = rem - b*tpb;
  const int y0 = (t / txc) * TH, x0t = (t % txc) * TWD;
  const int tid = threadIdx.x;
  const int tx = tid & (TWD/2 - 1), ty = tid / (TWD/2);
  const int cbase = sp * cpl;
  const size_t SS = (size_t)S*S;
  const float* Xb  = X  + (size_t)b*C*SS;
  const float* XPb = XP + (size_t)b*C*SS;
  const int py = y0 + ty, px = x0t + 2*tx;
  const size_t qoff = (size_t)py*S + px;

  // precompute fill slots (constant across channel chunks)
  int  f_lds[PER]; int f_go[PER]; bool f_ok[PER], f_val[PER];
  #pragma unroll
  for (int s = 0; s < PER; ++s) {
    int i = tid + s*NT;
    int r = i / HWC, c = i - r*HWC;
    int gy = y0 + r - 3, gx = x0t + c - 3;
    bool val = (i < NPOS);
    bool ok = val && gy >= 0 && gy < S && gx >= 0 && gx < S;
    f_val[s] = val; f_ok[s] = ok;
    f_go[s] = ok ? gy*S + gx : 0;
    f_lds[s] = val ? r*ST + c : 0;
  }

  floatx2 acc[49];
  #pragma unroll
  for (int d = 0; d < 49; ++d) acc[d] = (floatx2)0.0f;

  float fl[2][PER][2];
  float xc[4][2], xn[4][2];

#define FILL_LOAD(c0v) { \
  _Pragma("unroll") for (int pr = 0; pr < 2; ++pr) { \
    const float* p0_ = XPb + (size_t)(cbase + (c0v) + 2*pr)*SS; \
    const float* p1_ = p0_ + SS; \
    _Pragma("unroll") for (int s = 0; s < PER; ++s) { \
      fl[pr][s][0] = f_ok[s] ? p0_[f_go[s]] : 0.f; \
      fl[pr][s][1] = f_ok[s] ? p1_[f_go[s]] : 0.f; } } }

#define XLOAD(dst, c0v) { \
  _Pragma("unroll") for (int c = 0; c < 4; ++c) { \
    const float* q_ = Xb + (size_t)(cbase + (c0v) + c)*SS + qoff; \
    dst[c][0] = q_[0]; dst[c][1] = q_[1]; } }

#define FILL_STORE(bbv) { \
  _Pragma("unroll") for (int pr = 0; pr < 2; ++pr) \
    _Pragma("unroll") for (int s = 0; s < PER; ++s) \
      if (f_val[s]) ldsbuf[bbv][pr][f_lds[s]] = mkh2(fl[pr][s][0], fl[pr][s][1]); }

#define COMPUTE(bbv) { \
  _Pragma("unroll") for (int pr = 0; pr < 2; ++pr) { \
    half2_t xq0 = mkh2(xc[2*pr][0], xc[2*pr+1][0]); \
    half2_t xq1 = mkh2(xc[2*pr][1], xc[2*pr+1][1]); \
    _Pragma("unroll") for (int di = 0; di < 7; ++di) { \
      const half2_t* row_ = &ldsbuf[bbv][pr][(ty+di)*ST + 2*tx]; \
      half2_t w_[8]; \
      _Pragma("unroll") for (int k = 0; k < 4; ++k) { \
        half4_t v_ = *(const half4_t*)(row_ + 2*k); \
        w_[2*k]   = __builtin_shufflevector(v_, v_, 0, 1); \
        w_[2*k+1] = __builtin_shufflevector(v_, v_, 2, 3); } \
      _Pragma("unroll") for (int dj = 0; dj < 7; ++dj) { \
        acc[di*7+dj].x = fdot2f(xq0, w_[dj],   acc[di*7+dj].x); \
        acc[di*7+dj].y = fdot2f(xq1, w_[dj+1], acc[di*7+dj].y); } } } }

  const int nchunk = cpl >> 2;
  FILL_LOAD(0); XLOAD(xc, 0);
  FILL_STORE(0);
  FILL_LOAD(4); XLOAD(xn, 4);
  __syncthreads();
  for (int k = 0; k < nchunk; ++k) {
    const int bb = k & 1;
    if (k+1 < nchunk) FILL_STORE(bb^1);
    if (k+2 < nchunk) FILL_LOAD((k+2)*4);
    COMPUTE(bb);
    #pragma unroll
    for (int c = 0; c < 4; ++c) { xc[c][0] = xn[c][0]; xc[c][1] = xn[c][1]; }
    if (k+2 < nchunk) XLOAD(xn, (k+2)*4);
    __syncthreads();
  }
#undef FILL_LOAD
#undef XLOAD
#undef FILL_STORE
#undef COMPUTE

  float* P = partial + cfg.poff[lvl] + ((size_t)sp*8 + b)*49*SS + qoff;
  #pragma unroll
  for (int d = 0; d < 49; ++d)
    *(floatx2*)(P + (size_t)d*SS) = acc[d];
}

// ---------------------------------------------------------------------------
// Weight pack: w[196][98][3][3] fp32 -> bf16 MFMA B-fragments
// layout [lvl][t:14][s:36][lane:64][j:8], k = tap*128 + ch, N padded to 224.
// ---------------------------------------------------------------------------
__global__ __launch_bounds__(256)
void pack_w_kernel(const float* __restrict__ w0, const float* __restrict__ w1,
                   const float* __restrict__ w2, const float* __restrict__ w3,
                   const float* __restrict__ w4, const float* __restrict__ w5,
                   uint16_t* __restrict__ wpack)
{
  int idx = blockIdx.x*256 + threadIdx.x;
  int lvl = idx / 258048;
  int e = idx - lvl*258048;
  const float* W = lvl==0?w0:lvl==1?w1:lvl==2?w2:lvl==3?w3:lvl==4?w4:w5;
  int j = e & 7, lane = (e >> 3) & 63, rest = e >> 9;
  int s = rest % 36, tt = rest / 36;
  int n  = tt*16 + (lane & 15);
  int ch = (s & 3)*32 + (lane >> 4)*8 + j;
  int tap = s >> 2, ky = tap/3, kx = tap - 3*ky;
  float v = 0.f;
  if (n < 196 && ch < 98) v = W[((n*98 + ch)*3 + ky)*3 + kx];
  wpack[idx] = (uint16_t)f2bf(v);
}

// ---------------------------------------------------------------------------
// Pass2: one thread per (b, ch in [0,98), y, x). ch<49: sum split partials,
// leaky-relu, write corr fp32 output AND scatter bf16 into channels-last
// lstm_in [b][y+1][x+1][128]; ch>=49: scatter h. Halo/pad pre-zeroed by memset.
// ---------------------------------------------------------------------------
struct P2Cfg {
  int blk_start[7];
  int S[6], nsplit[6];
  long long poff[6], lstm_off[6], corr_off[6];
  const float* h[6];
};
__global__ __launch_bounds__(256)
void pass2_kernel(P2Cfg cfg, const float* __restrict__ partial,
                  uint16_t* __restrict__ lstm, float* __restrict__ dout)
{
  int blk = blockIdx.x;
  int lvl = 0;
  while (lvl < 5 && blk >= cfg.blk_start[lvl+1]) ++lvl;
  long long i = (long long)(blk - cfg.blk_start[lvl])*256 + threadIdx.x;
  const int S = cfg.S[lvl], Sp = S + 2, SS = S*S;
  if (i >= (long long)8*98*SS) return;
  int pix = (int)(i % SS);
  int ch  = (int)((i / SS) % 98);
  int b   = (int)(i / ((long long)98*SS));
  float val;
  if (ch < 49) {
    const int nsp = cfg.nsplit[lvl];
    const float* P = partial + cfg.poff[lvl] + ((size_t)b*49 + ch)*SS + pix;
    const size_t spstride = (size_t)8*49*SS;
    float s = 0.f;
    for (int sp = 0; sp < nsp; ++sp) s += P[(size_t)sp*spstride];
    s = s < 0.f ? 0.01f*s : s;
    dout[cfg.corr_off[lvl] + ((size_t)b*49 + ch)*SS + pix] = s;
    val = s;
  } else {
    val = cfg.h[lvl][((size_t)b*49 + (ch - 49))*SS + pix];
  }
  int y = pix / S, x = pix - y*S;
  lstm[cfg.lstm_off[lvl] + ((size_t)(b*Sp + y + 1)*Sp + (x + 1))*128 + ch] =
      (uint16_t)f2bf(val);
}

// ---------------------------------------------------------------------------
// Conv 3x3 (98->196) as implicit GEMM, bf16 MFMA 16x16x32, K = 9*128 = 1152,
// N padded to 224. No LDS/barriers; A direct from channels-last lstm_in,
// B from packed weights. Wave tile: 2 M-frags x 7 N-tiles (56 acc VGPR),
// explicit ping-pong prefetch over the 36 flattened K-steps.
// ---------------------------------------------------------------------------
struct CCfg {
  int wg_start[7];
  int S[6], tiles_x[6], tiles_pb[6], lwsh[6], mfc[6], mgrp[6];
  long long lstm_off[6], wp_off[6], conv_off[6];
};
__global__ __launch_bounds__(256)
void conv_kernel(CCfg cfg, const uint16_t* __restrict__ lstm,
                 const uint16_t* __restrict__ wpack, float* __restrict__ cout)
{
  int wg = blockIdx.x;
  int lvl = 0;
  while (lvl < 5 && wg >= cfg.wg_start[lvl+1]) ++lvl;
  wg -= cfg.wg_start[lvl];
  const int S = cfg.S[lvl], Sp = S + 2;
  const int lwsh = cfg.lwsh[lvl], msk = (1 << lwsh) - 1;
  const int tpb = cfg.tiles_pb[lvl];
  const int b = wg / tpb, t = wg - b*tpb;
  const int ty0 = (t / cfg.tiles_x[lvl]) << (6 - lwsh);
  const int tx0 = (t % cfg.tiles_x[lvl]) << lwsh;
  const int wave = threadIdx.x >> 6, lane = threadIdx.x & 63;
  const int nhalf = wave & 1, mhalf = wave >> 1;
  const int mfc = cfg.mfc[lvl];
  if (mhalf >= cfg.mgrp[lvl]) return;
  const int mi = lane & 15, q = lane >> 4;
  const int SS = S*S;
  const uint16_t* lb = lstm + cfg.lstm_off[lvl] + (size_t)b*Sp*Sp*128;
  int aoff[2];
  #pragma unroll
  for (int mf = 0; mf < 2; ++mf) {
    int p = mhalf*32 + mf*16 + mi;
    int pc = p < SS ? p : 0;                 // clamp (small-level pad)
    int y = ty0 + (pc >> lwsh), xx = tx0 + (pc & msk);
    aoff[mf] = (y*Sp + xx)*128 + q*8;
  }
  const uint16_t* wb = wpack + cfg.wp_off[lvl]
                     + (size_t)(nhalf*7)*36*512 + (size_t)lane*8;
  floatx4 acc[2][7];
  #pragma unroll
  for (int mf = 0; mf < 2; ++mf)
    #pragma unroll
    for (int nt = 0; nt < 7; ++nt) acc[mf][nt] = (floatx4)0.0f;

#define CONV_LOAD(sv, AV, BV) { \
  int tap_ = (sv) >> 2, cs_ = (sv) & 3; \
  int ky_ = tap_ / 3, kx_ = tap_ - 3*ky_; \
  int ao_ = ((ky_*Sp + kx_) << 7) + (cs_ << 5); \
  _Pragma("unroll") for (int mf = 0; mf < 2; ++mf) \
    if (mf < mfc) AV[mf] = *(const bf16x8*)(lb + aoff[mf] + ao_); \
  _Pragma("unroll") for (int nt = 0; nt < 7; ++nt) \
    BV[nt] = *(const bf16x8*)(wb + (size_t)((nt)*36 + (sv))*512); }

#define CONV_MFMA(AV, BV) { \
  _Pragma("unroll") for (int nt = 0; nt < 7; ++nt) \
    _Pragma("unroll") for (int mf = 0; mf < 2; ++mf) \
      if (mf < mfc) acc[mf][nt] = __builtin_amdgcn_mfma_f32_16x16x32_bf16( \
                        AV[mf], BV[nt], acc[mf][nt], 0, 0, 0); }

  bf16x8 av0[2], bv0[7], av1[2], bv1[7];
  CONV_LOAD(0, av0, bv0);
  for (int s = 0; s < 36; s += 2) {
    CONV_LOAD(s+1, av1, bv1);
    CONV_MFMA(av0, bv0);
    if (s+2 < 36) CONV_LOAD(s+2, av0, bv0);
    CONV_MFMA(av1, bv1);
  }
#undef CONV_LOAD
#undef CONV_MFMA

  float* co = cout + cfg.conv_off[lvl] + (size_t)b*196*SS;
  #pragma unroll
  for (int mf = 0; mf < 2; ++mf) {
    if (mf < mfc) {
      #pragma unroll
      for (int nt = 0; nt < 7; ++nt) {
        const int n = nhalf*112 + nt*16 + mi;
        if (n < 196) {
          #pragma unroll
          for (int r = 0; r < 4; ++r) {
            const int p = mhalf*32 + mf*16 + q*4 + r;  // D: row=q*4+r, col=lane&15
            if (p < SS) {
              const int y = ty0 + (p >> lwsh), xx = tx0 + (p & msk);
              co[(size_t)n*SS + y*S + xx] = acc[mf][nt][r];
            }
          }
        }
      }
    }
  }
}

// ---------------------------------------------------------------------------
// LSTM gates: conv + bias -> i,f,o,g -> h_next, c_next into d_out.
// ---------------------------------------------------------------------------
struct GCfg {
  int blk_start[7];
  int S[6];
  long long conv_off[6], h_off[6], c_off[6];
  const float* cpre[6]; const float* bias[6];
};
__global__ __launch_bounds__(256)
void gate_kernel(GCfg cfg, const float* __restrict__ convout, float* __restrict__ dout)
{
  int blk = blockIdx.x;
  int lvl = 0;
  while (lvl < 5 && blk >= cfg.blk_start[lvl+1]) ++lvl;
  long long e = (long long)(blk - cfg.blk_start[lvl])*256 + threadIdx.x;
  const int S = cfg.S[lvl];
  const int SS = S*S;
  if (e >= (long long)8*49*SS) return;
  int b = (int)(e / ((long long)49*SS));
  int r1 = (int)(e - (long long)b*49*SS);
  int ch = r1 / SS;
  int p  = r1 - ch*SS;
  const float* cv = convout + cfg.conv_off[lvl] + ((size_t)b*196 + ch)*SS + p;
  const float* bb = cfg.bias[lvl];
  float ci  = cv[0]              + bb[ch];
  float cf  = cv[(size_t)49*SS]  + bb[ch+49];
  float co_ = cv[(size_t)98*SS]  + bb[ch+98];
  float cg  = cv[(size_t)147*SS] + bb[ch+147];
  float ig = 1.f/(1.f + __expf(-ci));
  float fg = 1.f/(1.f + __expf(-cf));
  float og = 1.f/(1.f + __expf(-co_));
  float g  = 1.f - 2.f/(__expf(2.f*cg) + 1.f);
  float cp = cfg.cpre[lvl][e];
  float cn = fg*cp + ig*g;
  float hn = og * (1.f - 2.f/(__expf(2.f*cn) + 1.f));
  dout[cfg.h_off[lvl] + e] = hn;
  dout[cfg.c_off[lvl] + e] = cn;
}

// ---------------------------------------------------------------------------
extern "C" void kernel_launch(void* const* d_in, const int* in_sizes, int n_in,
                              void* d_out, int out_size, void* d_ws, size_t ws_size,
                              hipStream_t stream)
{
  const float *x[6], *xp[6], *h[6], *cpre[6], *w[6], *bias[6];
  for (int l = 0; l < 6; ++l) {
    x[l]    = (const float*)d_in[6*l + 0];
    xp[l]   = (const float*)d_in[6*l + 1];
    h[l]    = (const float*)d_in[6*l + 2];
    cpre[l] = (const float*)d_in[6*l + 3];
    w[l]    = (const float*)d_in[6*l + 4];
    bias[l] = (const float*)d_in[6*l + 5];
  }
  static const int SL[6] = {64,32,16,8,4,2};
  static const int CL[6] = {512,1024,512,256,256,256};
  int NSPL[6] = {8,16,16,1,1,1};

  long long hsz[6], lstm_off[6], conv_off[6], h_off[6], poff[6];
  long long a1 = 0, a2 = 0, a3 = 0;
  for (int l = 0; l < 6; ++l) {
    int S = SL[l], Sp = S + 2;
    hsz[l] = 8LL*49*S*S;
    lstm_off[l] = a1; a1 += 8LL*Sp*Sp*128;
    conv_off[l] = a2; a2 += 8LL*196*S*S;
    h_off[l]    = a3; a3 += hsz[l];
  }
  long long pa = 0;
  for (int l = 0; l < 6; ++l) { poff[l] = pa; pa += (long long)NSPL[l]*hsz[l]; }
  {
    long long pr_bytes = (pa > a2 ? pa : a2) * 4;
    long long need = a1*2 + 6LL*258048*2 + pr_bytes;
    if (need > (long long)ws_size) {      // fallback to smaller split config
      NSPL[0] = 4; NSPL[1] = 8; NSPL[2] = 16;
      pa = 0;
      for (int l = 0; l < 6; ++l) { poff[l] = pa; pa += (long long)NSPL[l]*hsz[l]; }
    }
  }
  const long long GRP = a3;            // floats per output group
  const long long LSTM_ELEMS = a1;     // bf16 elements

  uint16_t* lstm  = (uint16_t*)d_ws;
  uint16_t* wpack = (uint16_t*)((char*)d_ws + LSTM_ELEMS*2);
  float* partial  = (float*)((char*)d_ws + LSTM_ELEMS*2 + 6LL*258048*2);
  float* convout  = partial;  // partial fully consumed by pass2 before conv writes
  float* dout = (float*)d_out;

  // corr (all levels, one launch)
  {
    CorrCfg ccfg;
    static const int tpb[3] = {16, 4, 1};
    static const int txx[3] = {4, 2, 1};
    for (int l = 0; l < 6; ++l) { ccfg.gx[l] = x[l]; ccfg.gxp[l] = xp[l]; }
    int start = 0;
    for (int l = 0; l < 3; ++l) {
      ccfg.wg_start[l] = start;
      ccfg.S[l] = SL[l]; ccfg.C[l] = CL[l];
      ccfg.tiles_x[l] = txx[l]; ccfg.tiles_pb[l] = tpb[l];
      ccfg.cpl[l] = CL[l]/NSPL[l];
      ccfg.poff[l] = poff[l];
      start += NSPL[l]*8*tpb[l];
    }
    for (int l = 0; l < 3; ++l) {
      ccfg.small_start[l] = start;
      ccfg.sS[l] = SL[l+3]; ccfg.sC[l] = CL[l+3];
      ccfg.spoff[l] = poff[l+3];
      start += (int)((hsz[l+3] + 127)/128);
    }
    corr_kernel<16,16><<<start, 128, 0, stream>>>(ccfg, partial);
  }
  // zero lstm_in (halo + channel pad), then weight pack
  hipMemsetAsync(lstm, 0, (size_t)LSTM_ELEMS*2, stream);
  pack_w_kernel<<<6048, 256, 0, stream>>>(w[0],w[1],w[2],w[3],w[4],w[5], wpack);
  // pass2: partial sums -> leaky -> corr out + lstm_in scatter
  {
    P2Cfg p2; int start = 0;
    for (int l = 0; l < 6; ++l) {
      p2.blk_start[l] = start;
      start += (int)((8LL*98*SL[l]*SL[l] + 255)/256);
      p2.S[l] = SL[l]; p2.nsplit[l] = NSPL[l];
      p2.poff[l] = poff[l]; p2.lstm_off[l] = lstm_off[l];
      p2.corr_off[l] = 2*GRP + h_off[l];
      p2.h[l] = h[l];
    }
    p2.blk_start[6] = start;
    pass2_kernel<<<start, 256, 0, stream>>>(p2, partial, lstm, dout);
  }
  // conv (all levels, one launch)
  {
    CCfg cc;
    static const int ctpb[6] = {64, 16, 4, 1, 1, 1};
    static const int ctx[6]  = {4, 2, 1, 1, 1, 1};
    static const int clw[6]  = {4, 4, 4, 3, 2, 1};
    static const int cmfc[6] = {2, 2, 2, 2, 1, 1};
    static const int cmg[6]  = {2, 2, 2, 2, 1, 1};
    int start = 0;
    for (int l = 0; l < 6; ++l) {
      cc.wg_start[l] = start; start += 8*ctpb[l];
      cc.S[l] = SL[l]; cc.tiles_x[l] = ctx[l]; cc.tiles_pb[l] = ctpb[l];
      cc.lwsh[l] = clw[l]; cc.mfc[l] = cmfc[l]; cc.mgrp[l] = cmg[l];
      cc.lstm_off[l] = lstm_off[l];
      cc.wp_off[l] = 258048LL*l;
      cc.conv_off[l] = conv_off[l];
    }
    cc.wg_start[6] = start;
    conv_kernel<<<start, 256, 0, stream>>>(cc, lstm, wpack, convout);
  }
  // gates
  {
    GCfg gc; int start = 0;
    for (int l = 0; l < 6; ++l) {
      gc.blk_start[l] = start;
      start += (int)((hsz[l] + 255)/256);
      gc.S[l] = SL[l];
      gc.conv_off[l] = conv_off[l];
      gc.h_off[l] = h_off[l];
      gc.c_off[l] = GRP + h_off[l];
      gc.cpre[l] = cpre[l];
      gc.bias[l] = bias[l];
    }
    gc.blk_start[6] = start;
    gate_kernel<<<start, 256, 0, stream>>>(gc, convout, dout);
  }
  (void)in_sizes; (void)n_in; (void)out_size; (void)ws_size;
}

// Round 4
// 503.385 us; speedup vs baseline: 1.6548x; 1.0532x over previous
//
#include <hip/hip_runtime.h>
#include <stdint.h>

#define DEV __device__ __forceinline__

typedef _Float16 half2_t __attribute__((ext_vector_type(2)));
typedef _Float16 half4_t __attribute__((ext_vector_type(4)));
typedef __bf16   bf16x8  __attribute__((ext_vector_type(8)));
typedef float    floatx4 __attribute__((ext_vector_type(4)));
typedef float    floatx2 __attribute__((ext_vector_type(2)));

DEV float fdot2f(half2_t a, half2_t b, float c) {
#if __has_builtin(__builtin_amdgcn_fdot2)
  return __builtin_amdgcn_fdot2(a, b, c, false);
#else
  return c + (float)a[0] * (float)b[0] + (float)a[1] * (float)b[1];
#endif
}

DEV half2_t pkh2(float a, float b) {
#if __has_builtin(__builtin_amdgcn_cvt_pkrtz)
  return __builtin_bit_cast(half2_t, __builtin_amdgcn_cvt_pkrtz(a, b));
#else
  half2_t r; r[0] = (_Float16)a; r[1] = (_Float16)b; return r;
#endif
}

DEV uint32_t f2bf(float f) {  // fp32 -> bf16 bits, RNE
  uint32_t u = __float_as_uint(f);
  return (u + 0x7FFFu + ((u >> 16) & 1u)) >> 16;
}

// ---------------------------------------------------------------------------
// Correlation (all levels, one launch).
// Big levels: 16x16 px tile, 128 thr (2 px/thr), channel-split across blocks,
// double-buffered LDS, float4-pair vectorized halo fill, f16 partials out.
// Small levels (l3..l5): one thread per (b,d,y,x), loop C.
// ---------------------------------------------------------------------------
struct CorrCfg {
  const float* gx[6]; const float* gxp[6];
  int wg_start[3];    // big-level block starts
  int small_start[3]; // small-level block starts
  int S[3], C[3], tiles_x[3], tiles_pb[3], cpl[3];
  int sS[3], sC[3];
  long long poff[3], spoff[3];
};

template<int TH, int TWD>
__global__ __launch_bounds__(128)
void corr_kernel(CorrCfg cfg, _Float16* __restrict__ partial)
{
  int wg = blockIdx.x;
  if (wg >= cfg.small_start[0]) {
    // ---- small path ----
    int lvl = (wg >= cfg.small_start[2]) ? 2 : (wg >= cfg.small_start[1]) ? 1 : 0;
    long long i = (long long)(wg - cfg.small_start[lvl])*128 + threadIdx.x;
    const int S = cfg.sS[lvl], C = cfg.sC[lvl], SS = S*S;
    if (i >= (long long)8*49*SS) return;
    const float* X  = cfg.gx[lvl+3];
    const float* XP = cfg.gxp[lvl+3];
    int xc_ = (int)(i % S); int yc = (int)((i/S) % S);
    int d = (int)((i/SS) % 49); int b = (int)(i/((long long)49*SS));
    int yy = yc + d/7 - 3, xx = xc_ + (d%7) - 3;
    float s = 0.f;
    if (yy >= 0 && yy < S && xx >= 0 && xx < S) {
      const float* xb = X  + (size_t)b*C*SS + (size_t)yc*S + xc_;
      const float* pb = XP + (size_t)b*C*SS + (size_t)yy*S + xx;
      #pragma unroll 8
      for (int c = 0; c < C; ++c) s += xb[(size_t)c*SS] * pb[(size_t)c*SS];
    }
    partial[cfg.spoff[lvl] + i] = (_Float16)s;
    return;
  }
  // ---- big path ----
  constexpr int NT  = 128;
  constexpr int ROWS = TH + 6;            // 22
  constexpr int COLS = TWD + 6;           // 22 used cols
  constexpr int ST   = TWD + 10;          // 26 half2 row stride
  constexpr int SLOTS = ROWS * 6 * 2;     // rows x quads x ch-pairs = 264
  constexpr int PER   = (SLOTS + NT - 1)/NT;  // 3
  __shared__ half2_t ldsbuf[2][2][ROWS*ST] __attribute__((aligned(16)));

  int lvl = (wg >= cfg.wg_start[2]) ? 2 : (wg >= cfg.wg_start[1]) ? 1 : 0;
  wg -= cfg.wg_start[lvl];
  const float* X  = cfg.gx[lvl];
  const float* XP = cfg.gxp[lvl];
  const int S = cfg.S[lvl], C = cfg.C[lvl];
  const int txc = cfg.tiles_x[lvl], tpb = cfg.tiles_pb[lvl], cpl = cfg.cpl[lvl];
  const int per_split = 8 * tpb;
  const int sp = wg / per_split;
  const int rem = wg - sp*per_split;
  const int b = rem / tpb;
  const int t = rem - b*tpb;
  const int y0 = (t / txc) * TH, x0t = (t % txc) * TWD;
  const int tid = threadIdx.x;
  const int tx = tid & (TWD/2 - 1), ty = tid / (TWD/2);
  const int cbase = sp * cpl;
  const size_t SS = (size_t)S*S;
  const float* Xb  = X  + (size_t)b*C*SS;
  const float* XPb = XP + (size_t)b*C*SS;
  const int py = y0 + ty, px = x0t + 2*tx;
  const size_t qoff = (size_t)py*S + px;

  // fill-slot geometry (constant across channel chunks)
  int f_go[PER], f_base[PER], f_col0[PER], f_pr[PER];
  bool f_ok[PER], f_val[PER];
  #pragma unroll
  for (int s = 0; s < PER; ++s) {
    int i = tid + s*NT;
    bool val = (i < SLOTS);
    int ii = val ? i : 0;
    int pr = ii & 1;
    int rest = ii >> 1;
    int q = rest % 6;
    int r = rest / 6;
    int gy = y0 + r - 3;
    int gx0 = x0t - 4 + 4*q;
    bool ok = val && gy >= 0 && gy < S && gx0 >= 0 && (gx0 + 3) < S;
    f_val[s] = val; f_ok[s] = ok; f_pr[s] = pr;
    f_go[s] = ok ? gy*S + gx0 : 0;
    f_col0[s] = 4*q - 1;
    f_base[s] = r*ST;
  }

  floatx2 acc[49];
  #pragma unroll
  for (int d = 0; d < 49; ++d) acc[d] = (floatx2)0.0f;

  floatx4 fl[PER][2];
  floatx2 xc[4], xn[4];

#define FILL_LOAD(c0v) { \
  _Pragma("unroll") for (int s = 0; s < PER; ++s) { \
    const float* p_ = XPb + (size_t)(cbase + (c0v) + 2*f_pr[s])*SS + f_go[s]; \
    if (f_ok[s]) { fl[s][0] = *(const floatx4*)p_; fl[s][1] = *(const floatx4*)(p_ + SS); } \
    else { fl[s][0] = (floatx4)0.f; fl[s][1] = (floatx4)0.f; } } }

#define XLOAD(dst, c0v) { \
  _Pragma("unroll") for (int c = 0; c < 4; ++c) \
    dst[c] = *(const floatx2*)(Xb + (size_t)(cbase + (c0v) + c)*SS + qoff); }

#define FILL_STORE(bbv) { \
  _Pragma("unroll") for (int s = 0; s < PER; ++s) if (f_val[s]) { \
    half2_t* plane_ = &ldsbuf[bbv][f_pr[s]][0]; \
    _Pragma("unroll") for (int j = 0; j < 4; ++j) { \
      int col_ = f_col0[s] + j; \
      if (col_ >= 0 && col_ < COLS) \
        plane_[f_base[s] + col_] = pkh2(fl[s][0][j], fl[s][1][j]); } } }

#define COMPUTE(bbv) { \
  _Pragma("unroll") for (int pr = 0; pr < 2; ++pr) { \
    half2_t xq0 = pkh2(xc[2*pr].x, xc[2*pr+1].x); \
    half2_t xq1 = pkh2(xc[2*pr].y, xc[2*pr+1].y); \
    _Pragma("unroll") for (int di = 0; di < 7; ++di) { \
      const half2_t* row_ = &ldsbuf[bbv][pr][(ty+di)*ST + 2*tx]; \
      half2_t w_[8]; \
      _Pragma("unroll") for (int k = 0; k < 4; ++k) { \
        half4_t v_ = *(const half4_t*)(row_ + 2*k); \
        w_[2*k]   = __builtin_shufflevector(v_, v_, 0, 1); \
        w_[2*k+1] = __builtin_shufflevector(v_, v_, 2, 3); } \
      _Pragma("unroll") for (int dj = 0; dj < 7; ++dj) { \
        acc[di*7+dj].x = fdot2f(xq0, w_[dj],   acc[di*7+dj].x); \
        acc[di*7+dj].y = fdot2f(xq1, w_[dj+1], acc[di*7+dj].y); } } } }

  const int nchunk = cpl >> 2;
  FILL_LOAD(0); XLOAD(xc, 0);
  FILL_STORE(0);
  FILL_LOAD(4); XLOAD(xn, 4);
  __syncthreads();
  for (int k = 0; k < nchunk; ++k) {
    const int bb = k & 1;
    if (k+1 < nchunk) FILL_STORE(bb^1);
    if (k+2 < nchunk) FILL_LOAD((k+2)*4);
    COMPUTE(bb);
    #pragma unroll
    for (int c = 0; c < 4; ++c) xc[c] = xn[c];
    if (k+2 < nchunk) XLOAD(xn, (k+2)*4);
    __syncthreads();
  }
#undef FILL_LOAD
#undef XLOAD
#undef FILL_STORE
#undef COMPUTE

  _Float16* P = partial + cfg.poff[lvl] + ((size_t)sp*8 + b)*49*SS + qoff;
  #pragma unroll
  for (int d = 0; d < 49; ++d) {
    half2_t pk = pkh2(acc[d].x, acc[d].y);
    *(uint32_t*)(P + (size_t)d*SS) = *(const uint32_t*)&pk;
  }
}

// ---------------------------------------------------------------------------
// Weight pack: w[196][98][3][3] fp32 -> bf16 MFMA B-fragments
// layout [lvl][t:14][s:36][lane:64][j:8], k = tap*128 + ch, N padded to 224.
// ---------------------------------------------------------------------------
__global__ __launch_bounds__(256)
void pack_w_kernel(const float* __restrict__ w0, const float* __restrict__ w1,
                   const float* __restrict__ w2, const float* __restrict__ w3,
                   const float* __restrict__ w4, const float* __restrict__ w5,
                   uint16_t* __restrict__ wpack)
{
  int idx = blockIdx.x*256 + threadIdx.x;
  int lvl = idx / 258048;
  int e = idx - lvl*258048;
  const float* W = lvl==0?w0:lvl==1?w1:lvl==2?w2:lvl==3?w3:lvl==4?w4:w5;
  int j = e & 7, lane = (e >> 3) & 63, rest = e >> 9;
  int s = rest % 36, tt = rest / 36;
  int n  = tt*16 + (lane & 15);
  int ch = (s & 3)*32 + (lane >> 4)*8 + j;
  int tap = s >> 2, ky = tap/3, kx = tap - 3*ky;
  float v = 0.f;
  if (n < 196 && ch < 98) v = W[((n*98 + ch)*3 + ky)*3 + kx];
  wpack[idx] = (uint16_t)f2bf(v);
}

// ---------------------------------------------------------------------------
// Pass2: block = (lvl, b, pixel-group). Stage A: coalesced gather of split
// partials (f16) -> fp32 sum -> leaky -> corr out (coalesced) + LDS[px][99];
// h gathered likewise. Stage B: wave-per-pixel packed bf16x2 u32 stores into
// channels-last lstm_in [b][y+1][x+1][128] (fully coalesced 256B/instr).
// ---------------------------------------------------------------------------
struct P2Cfg {
  int blk_start[7];
  int S[6], nsplit[6], pxg[6], lg[6], gpb[6];
  long long poff[6], lstm_off[6], corr_off[6];
  const float* h[6];
};
__global__ __launch_bounds__(256)
void pass2_kernel(P2Cfg cfg, const _Float16* __restrict__ partial,
                  uint32_t* __restrict__ lstm, float* __restrict__ dout)
{
  __shared__ float lds[64*99];
  int blk = blockIdx.x;
  int lvl = 0;
  while (lvl < 5 && blk >= cfg.blk_start[lvl+1]) ++lvl;
  int rel = blk - cfg.blk_start[lvl];
  const int S = cfg.S[lvl], Sp = S + 2, SS = S*S;
  const int PXG = cfg.pxg[lvl], lg = cfg.lg[lvl], gpb = cfg.gpb[lvl];
  const int b = rel / gpb, g = rel - b*gpb;
  const int pixbase = g * PXG;
  const int tid = threadIdx.x;
  const int nsp = cfg.nsplit[lvl];
  const size_t spstride = (size_t)8*49*SS;
  // stage A
  for (int e = tid; e < PXG*98; e += 256) {
    int pxl = e & (PXG-1);
    int ch  = e >> lg;
    int pix = pixbase + pxl;
    float v;
    if (ch < 49) {
      const _Float16* P = partial + cfg.poff[lvl] + ((size_t)b*49 + ch)*SS + pix;
      float s = 0.f;
      for (int sp = 0; sp < nsp; ++sp) s += (float)P[(size_t)sp*spstride];
      s = s < 0.f ? 0.01f*s : s;
      dout[cfg.corr_off[lvl] + ((size_t)b*49 + ch)*SS + pix] = s;
      v = s;
    } else {
      v = cfg.h[lvl][((size_t)b*49 + (ch - 49))*SS + pix];
    }
    lds[pxl*99 + ch] = v;
  }
  __syncthreads();
  // stage B
  uint32_t* Lb = lstm + (cfg.lstm_off[lvl] >> 1);
  for (int f = tid; f < (PXG << 6); f += 256) {
    int pxl = f >> 6, c2 = f & 63;
    int pix = pixbase + pxl;
    int y = pix / S, x = pix - y*S;
    int c0 = 2*c2, c1 = c0 + 1;
    float v0 = c0 < 98 ? lds[pxl*99 + c0] : 0.f;
    float v1 = c1 < 98 ? lds[pxl*99 + c1] : 0.f;
    Lb[((size_t)(b*Sp + y + 1)*Sp + (x + 1))*64 + c2] = f2bf(v0) | (f2bf(v1) << 16);
  }
}

// ---------------------------------------------------------------------------
// Conv 3x3 (98->196) as implicit GEMM, bf16 MFMA 16x16x32, K = 9*128 = 1152,
// N padded to 224. No LDS/barriers; A direct from channels-last lstm_in,
// B from packed weights. Wave tile: 2 M-frags x 7 N-tiles (56 acc VGPR),
// explicit ping-pong prefetch over the 36 flattened K-steps.
// ---------------------------------------------------------------------------
struct CCfg {
  int wg_start[7];
  int S[6], tiles_x[6], tiles_pb[6], lwsh[6], mfc[6], mgrp[6];
  long long lstm_off[6], wp_off[6], conv_off[6];
};
__global__ __launch_bounds__(256)
void conv_kernel(CCfg cfg, const uint16_t* __restrict__ lstm,
                 const uint16_t* __restrict__ wpack, float* __restrict__ cout)
{
  int wg = blockIdx.x;
  int lvl = 0;
  while (lvl < 5 && wg >= cfg.wg_start[lvl+1]) ++lvl;
  wg -= cfg.wg_start[lvl];
  const int S = cfg.S[lvl], Sp = S + 2;
  const int lwsh = cfg.lwsh[lvl], msk = (1 << lwsh) - 1;
  const int tpb = cfg.tiles_pb[lvl];
  const int b = wg / tpb, t = wg - b*tpb;
  const int ty0 = (t / cfg.tiles_x[lvl]) << (6 - lwsh);
  const int tx0 = (t % cfg.tiles_x[lvl]) << lwsh;
  const int wave = threadIdx.x >> 6, lane = threadIdx.x & 63;
  const int nhalf = wave & 1, mhalf = wave >> 1;
  const int mfc = cfg.mfc[lvl];
  if (mhalf >= cfg.mgrp[lvl]) return;
  const int mi = lane & 15, q = lane >> 4;
  const int SS = S*S;
  const uint16_t* lb = lstm + cfg.lstm_off[lvl] + (size_t)b*Sp*Sp*128;
  int aoff[2];
  #pragma unroll
  for (int mf = 0; mf < 2; ++mf) {
    int p = mhalf*32 + mf*16 + mi;
    int pc = p < SS ? p : 0;                 // clamp (small-level pad)
    int y = ty0 + (pc >> lwsh), xx = tx0 + (pc & msk);
    aoff[mf] = (y*Sp + xx)*128 + q*8;
  }
  const uint16_t* wb = wpack + cfg.wp_off[lvl]
                     + (size_t)(nhalf*7)*36*512 + (size_t)lane*8;
  floatx4 acc[2][7];
  #pragma unroll
  for (int mf = 0; mf < 2; ++mf)
    #pragma unroll
    for (int nt = 0; nt < 7; ++nt) acc[mf][nt] = (floatx4)0.0f;

#define CONV_LOAD(sv, AV, BV) { \
  int tap_ = (sv) >> 2, cs_ = (sv) & 3; \
  int ky_ = tap_ / 3, kx_ = tap_ - 3*ky_; \
  int ao_ = ((ky_*Sp + kx_) << 7) + (cs_ << 5); \
  _Pragma("unroll") for (int mf = 0; mf < 2; ++mf) \
    if (mf < mfc) AV[mf] = *(const bf16x8*)(lb + aoff[mf] + ao_); \
  _Pragma("unroll") for (int nt = 0; nt < 7; ++nt) \
    BV[nt] = *(const bf16x8*)(wb + (size_t)((nt)*36 + (sv))*512); }

#define CONV_MFMA(AV, BV) { \
  _Pragma("unroll") for (int nt = 0; nt < 7; ++nt) \
    _Pragma("unroll") for (int mf = 0; mf < 2; ++mf) \
      if (mf < mfc) acc[mf][nt] = __builtin_amdgcn_mfma_f32_16x16x32_bf16( \
                        AV[mf], BV[nt], acc[mf][nt], 0, 0, 0); }

  bf16x8 av0[2], bv0[7], av1[2], bv1[7];
  CONV_LOAD(0, av0, bv0);
  for (int s = 0; s < 36; s += 2) {
    CONV_LOAD(s+1, av1, bv1);
    CONV_MFMA(av0, bv0);
    if (s+2 < 36) CONV_LOAD(s+2, av0, bv0);
    CONV_MFMA(av1, bv1);
  }
#undef CONV_LOAD
#undef CONV_MFMA

  float* co = cout + cfg.conv_off[lvl] + (size_t)b*196*SS;
  #pragma unroll
  for (int mf = 0; mf < 2; ++mf) {
    if (mf < mfc) {
      #pragma unroll
      for (int nt = 0; nt < 7; ++nt) {
        const int n = nhalf*112 + nt*16 + mi;
        if (n < 196) {
          #pragma unroll
          for (int r = 0; r < 4; ++r) {
            const int p = mhalf*32 + mf*16 + q*4 + r;  // D: row=q*4+r, col=lane&15
            if (p < SS) {
              const int y = ty0 + (p >> lwsh), xx = tx0 + (p & msk);
              co[(size_t)n*SS + y*S + xx] = acc[mf][nt][r];
            }
          }
        }
      }
    }
  }
}

// ---------------------------------------------------------------------------
// LSTM gates: conv + bias -> i,f,o,g -> h_next, c_next into d_out.
// ---------------------------------------------------------------------------
struct GCfg {
  int blk_start[7];
  int S[6];
  long long conv_off[6], h_off[6], c_off[6];
  const float* cpre[6]; const float* bias[6];
};
__global__ __launch_bounds__(256)
void gate_kernel(GCfg cfg, const float* __restrict__ convout, float* __restrict__ dout)
{
  int blk = blockIdx.x;
  int lvl = 0;
  while (lvl < 5 && blk >= cfg.blk_start[lvl+1]) ++lvl;
  long long e = (long long)(blk - cfg.blk_start[lvl])*256 + threadIdx.x;
  const int S = cfg.S[lvl];
  const int SS = S*S;
  if (e >= (long long)8*49*SS) return;
  int b = (int)(e / ((long long)49*SS));
  int r1 = (int)(e - (long long)b*49*SS);
  int ch = r1 / SS;
  int p  = r1 - ch*SS;
  const float* cv = convout + cfg.conv_off[lvl] + ((size_t)b*196 + ch)*SS + p;
  const float* bb = cfg.bias[lvl];
  float ci  = cv[0]              + bb[ch];
  float cf  = cv[(size_t)49*SS]  + bb[ch+49];
  float co_ = cv[(size_t)98*SS]  + bb[ch+98];
  float cg  = cv[(size_t)147*SS] + bb[ch+147];
  float ig = 1.f/(1.f + __expf(-ci));
  float fg = 1.f/(1.f + __expf(-cf));
  float og = 1.f/(1.f + __expf(-co_));
  float g  = 1.f - 2.f/(__expf(2.f*cg) + 1.f);
  float cp = cfg.cpre[lvl][e];
  float cn = fg*cp + ig*g;
  float hn = og * (1.f - 2.f/(__expf(2.f*cn) + 1.f));
  dout[cfg.h_off[lvl] + e] = hn;
  dout[cfg.c_off[lvl] + e] = cn;
}

// ---------------------------------------------------------------------------
extern "C" void kernel_launch(void* const* d_in, const int* in_sizes, int n_in,
                              void* d_out, int out_size, void* d_ws, size_t ws_size,
                              hipStream_t stream)
{
  const float *x[6], *xp[6], *h[6], *cpre[6], *w[6], *bias[6];
  for (int l = 0; l < 6; ++l) {
    x[l]    = (const float*)d_in[6*l + 0];
    xp[l]   = (const float*)d_in[6*l + 1];
    h[l]    = (const float*)d_in[6*l + 2];
    cpre[l] = (const float*)d_in[6*l + 3];
    w[l]    = (const float*)d_in[6*l + 4];
    bias[l] = (const float*)d_in[6*l + 5];
  }
  static const int SL[6] = {64,32,16,8,4,2};
  static const int CL[6] = {512,1024,512,256,256,256};
  int NSPL[6] = {8,16,16,1,1,1};

  long long hsz[6], lstm_off[6], conv_off[6], h_off[6], poff[6];
  long long a1 = 0, a2 = 0, a3 = 0;
  for (int l = 0; l < 6; ++l) {
    int S = SL[l], Sp = S + 2;
    hsz[l] = 8LL*49*S*S;
    lstm_off[l] = a1; a1 += 8LL*Sp*Sp*128;
    conv_off[l] = a2; a2 += 8LL*196*S*S;
    h_off[l]    = a3; a3 += hsz[l];
  }
  long long pa = 0;
  for (int l = 0; l < 6; ++l) { poff[l] = pa; pa += (long long)NSPL[l]*hsz[l]; }
  {
    long long pr_bytes = (pa*2 > a2*4 ? pa*2 : a2*4);
    long long need = a1*2 + 6LL*258048*2 + pr_bytes;
    if (need > (long long)ws_size) {      // fallback to smaller split config
      NSPL[0] = 4; NSPL[1] = 8; NSPL[2] = 16;
      pa = 0;
      for (int l = 0; l < 6; ++l) { poff[l] = pa; pa += (long long)NSPL[l]*hsz[l]; }
    }
  }
  const long long GRP = a3;            // floats per output group
  const long long LSTM_ELEMS = a1;     // bf16 elements

  uint16_t* lstm  = (uint16_t*)d_ws;
  uint16_t* wpack = (uint16_t*)((char*)d_ws + LSTM_ELEMS*2);
  _Float16* partial = (_Float16*)((char*)d_ws + LSTM_ELEMS*2 + 6LL*258048*2);
  float* convout  = (float*)partial;  // partial consumed by pass2 before conv writes
  float* dout = (float*)d_out;

  // corr (all levels, one launch)
  {
    CorrCfg ccfg;
    static const int tpb[3] = {16, 4, 1};
    static const int txx[3] = {4, 2, 1};
    for (int l = 0; l < 6; ++l) { ccfg.gx[l] = x[l]; ccfg.gxp[l] = xp[l]; }
    int start = 0;
    for (int l = 0; l < 3; ++l) {
      ccfg.wg_start[l] = start;
      ccfg.S[l] = SL[l]; ccfg.C[l] = CL[l];
      ccfg.tiles_x[l] = txx[l]; ccfg.tiles_pb[l] = tpb[l];
      ccfg.cpl[l] = CL[l]/NSPL[l];
      ccfg.poff[l] = poff[l];
      start += NSPL[l]*8*tpb[l];
    }
    for (int l = 0; l < 3; ++l) {
      ccfg.small_start[l] = start;
      ccfg.sS[l] = SL[l+3]; ccfg.sC[l] = CL[l+3];
      ccfg.spoff[l] = poff[l+3];
      start += (int)((hsz[l+3] + 127)/128);
    }
    corr_kernel<16,16><<<start, 128, 0, stream>>>(ccfg, partial);
  }
  // zero lstm_in (halo + channel pad), then weight pack
  (void)hipMemsetAsync(lstm, 0, (size_t)LSTM_ELEMS*2, stream);
  pack_w_kernel<<<6048, 256, 0, stream>>>(w[0],w[1],w[2],w[3],w[4],w[5], wpack);
  // pass2: partial sums -> leaky -> corr out + lstm_in (coalesced via LDS)
  {
    P2Cfg p2; int start = 0;
    static const int PXGL[6] = {64,64,64,64,16,4};
    static const int LGL[6]  = {6,6,6,6,4,2};
    for (int l = 0; l < 6; ++l) {
      p2.blk_start[l] = start;
      int gpb = (SL[l]*SL[l]) / PXGL[l]; if (gpb < 1) gpb = 1;
      p2.gpb[l] = gpb;
      start += 8 * gpb;
      p2.S[l] = SL[l]; p2.nsplit[l] = NSPL[l];
      p2.pxg[l] = PXGL[l]; p2.lg[l] = LGL[l];
      p2.poff[l] = poff[l]; p2.lstm_off[l] = lstm_off[l];
      p2.corr_off[l] = 2*GRP + h_off[l];
      p2.h[l] = h[l];
    }
    p2.blk_start[6] = start;
    pass2_kernel<<<start, 256, 0, stream>>>(p2, partial, (uint32_t*)lstm, dout);
  }
  // conv (all levels, one launch)
  {
    CCfg cc;
    static const int ctpb[6] = {64, 16, 4, 1, 1, 1};
    static const int ctx[6]  = {4, 2, 1, 1, 1, 1};
    static const int clw[6]  = {4, 4, 4, 3, 2, 1};
    static const int cmfc[6] = {2, 2, 2, 2, 1, 1};
    static const int cmg[6]  = {2, 2, 2, 2, 1, 1};
    int start = 0;
    for (int l = 0; l < 6; ++l) {
      cc.wg_start[l] = start; start += 8*ctpb[l];
      cc.S[l] = SL[l]; cc.tiles_x[l] = ctx[l]; cc.tiles_pb[l] = ctpb[l];
      cc.lwsh[l] = clw[l]; cc.mfc[l] = cmfc[l]; cc.mgrp[l] = cmg[l];
      cc.lstm_off[l] = lstm_off[l];
      cc.wp_off[l] = 258048LL*l;
      cc.conv_off[l] = conv_off[l];
    }
    cc.wg_start[6] = start;
    conv_kernel<<<start, 256, 0, stream>>>(cc, lstm, wpack, convout);
  }
  // gates
  {
    GCfg gc; int start = 0;
    for (int l = 0; l < 6; ++l) {
      gc.blk_start[l] = start;
      start += (int)((hsz[l] + 255)/256);
      gc.S[l] = SL[l];
      gc.conv_off[l] = conv_off[l];
      gc.h_off[l] = h_off[l];
      gc.c_off[l] = GRP + h_off[l];
      gc.cpre[l] = cpre[l];
      gc.bias[l] = bias[l];
    }
    gc.blk_start[6] = start;
    gate_kernel<<<start, 256, 0, stream>>>(gc, convout, dout);
  }
  (void)in_sizes; (void)n_in; (void)out_size; (void)ws_size;
}